// Round 5
// baseline (359.669 us; speedup 1.0000x reference)
//
#include <hip/hip_runtime.h>

// GCN forward: x[50000,256] -> enc(256->128)+lrelu -> 2x GCNConv(128->128)+lrelu -> dec(128->64)
// f32 in/out. GEMMs: bf16 MFMA (16x16x32), hi/lo truncation-split (error ~2^-16):
//   a = ahi + alo (+ eps<=2^-16|a|);  A@W ~= Ahi@Whi + Ahi@Wlo + Alo@Whi
// Each wave computes 64 rows (TM=4 row-tiles) so each weight-fragment load feeds 12 MFMAs.
// Aggregation: CSR-over-dst + gather; t stored bf16 (halves per-XCD compulsory L2-miss traffic).

constexpr int HID = 128;
constexpr float NEG = 0.1f;

typedef __attribute__((ext_vector_type(8))) short short8;  // 8 bf16 (4 VGPRs)
typedef __attribute__((ext_vector_type(4))) float f32x4;   // MFMA C/D

union frag8 { short8 s; unsigned u[4]; };

__device__ __forceinline__ float lrelu(float v) { return v > 0.f ? v : v * NEG; }

__device__ __forceinline__ unsigned fbits(float f) {
  union { float f; unsigned u; } c; c.f = f; return c.u;
}
__device__ __forceinline__ unsigned short f2bf(float f) {  // f32 -> bf16, RNE
  unsigned u = fbits(f);
  return (unsigned short)((u + 0x7fffu + ((u >> 16) & 1u)) >> 16);
}
__device__ __forceinline__ float bf2f(unsigned short h) {
  union { unsigned u; float f; } c; c.u = ((unsigned)h) << 16; return c.f;
}

// ---- degree ----
__global__ __launch_bounds__(256) void k_deg(const int* __restrict__ dst, int E,
                                             int* __restrict__ deg) {
  int i = blockIdx.x * 256 + threadIdx.x;
  if (i < E) atomicAdd(&deg[dst[i]], 1);
}

// ---- exclusive prefix scan over deg -> rowptr (+dinv fused) ----
__global__ __launch_bounds__(256) void k_scan1(const int* __restrict__ deg, int N,
                                               int* __restrict__ rowptr,
                                               int* __restrict__ bsum,
                                               float* __restrict__ dinv) {
  __shared__ int s[256];
  int i = blockIdx.x * 256 + threadIdx.x;
  int v = (i < N) ? deg[i] : 0;
  s[threadIdx.x] = v;
  __syncthreads();
#pragma unroll
  for (int off = 1; off < 256; off <<= 1) {
    int t = (threadIdx.x >= off) ? s[threadIdx.x - off] : 0;
    __syncthreads();
    s[threadIdx.x] += t;
    __syncthreads();
  }
  if (i < N) {
    rowptr[i] = s[threadIdx.x] - v;     // exclusive
    dinv[i] = rsqrtf((float)v + 1.0f);  // +1 for self-loop
  }
  if (threadIdx.x == 255) bsum[blockIdx.x] = s[255];
}

__global__ __launch_bounds__(256) void k_scan2(const int* __restrict__ bsum,
                                               int* __restrict__ boff, int nb) {
  __shared__ int s[256];
  int i = threadIdx.x;
  int v = (i < nb) ? bsum[i] : 0;
  s[i] = v;
  __syncthreads();
#pragma unroll
  for (int off = 1; off < 256; off <<= 1) {
    int t = (i >= off) ? s[i - off] : 0;
    __syncthreads();
    s[i] += t;
    __syncthreads();
  }
  if (i < nb) boff[i] = s[i] - v;
}

__global__ __launch_bounds__(256) void k_scan3(int* __restrict__ rowptr,
                                               const int* __restrict__ boff, int N) {
  int i = blockIdx.x * 256 + threadIdx.x;
  if (i < N) rowptr[i] += boff[blockIdx.x];
}

// ---- CSR fill ----
__global__ __launch_bounds__(256) void k_fill(const int* __restrict__ src,
                                              const int* __restrict__ dst, int E,
                                              const int* __restrict__ rowptr,
                                              int* __restrict__ cursor,
                                              int* __restrict__ eidx) {
  int e = blockIdx.x * 256 + threadIdx.x;
  if (e >= E) return;
  int d = dst[e];
  int pos = atomicAdd(&cursor[d], 1);
  eidx[rowptr[d] + pos] = src[e];
}

// ---- fused weight swizzle (all 4 matrices, one launch) ----
// wf index: ((ks*NT + nt)*64 + lane)*16 ; [0..7]=hi (RNE), [8..15]=lo
__global__ __launch_bounds__(256) void k_wconv_all(const float* __restrict__ encW,
                                                   const float* __restrict__ convW,
                                                   const float* __restrict__ decW,
                                                   unsigned short* __restrict__ wf_enc,
                                                   unsigned short* __restrict__ wf_c0,
                                                   unsigned short* __restrict__ wf_c1,
                                                   unsigned short* __restrict__ wf_dec) {
  int idx = blockIdx.x * 256 + threadIdx.x;
  const float* W; unsigned short* wf; int N, NT, base;
  if (idx < 4096)      { W = encW;          wf = wf_enc; N = 128; NT = 8; base = idx; }
  else if (idx < 6144) { W = convW;         wf = wf_c0;  N = 128; NT = 8; base = idx - 4096; }
  else if (idx < 8192) { W = convW + 16384; wf = wf_c1;  N = 128; NT = 8; base = idx - 6144; }
  else if (idx < 9216) { W = decW;          wf = wf_dec; N = 64;  NT = 4; base = idx - 8192; }
  else return;
  int lane = base & 63, tile = base >> 6;
  int nt = tile % NT, ks = tile / NT;
  int col = nt * 16 + (lane & 15);
  int krow = ks * 32 + (lane >> 4) * 8;
  unsigned short* o = wf + (size_t)base * 16;
#pragma unroll
  for (int j = 0; j < 8; ++j) {
    float v = W[(size_t)(krow + j) * N + col];
    unsigned short hi = f2bf(v);
    o[j] = hi;
    o[8 + j] = f2bf(v - bf2f(hi));
  }
}

// ---- MFMA GEMM: 1 wave/block, 64 rows/block (TM=4 x 16), C[M][NT*16] = A[M][K] @ W ----
// MODE 0: C = lrelu(acc + bias)        f32 out (encoder)
// MODE 1: C = bf16(acc * dinv[row])    bf16 out (conv -> t)
// MODE 2: C = acc + bias               f32 out (decoder)
template <int NT, int MODE>
__global__ __launch_bounds__(64, 2) void k_mfma(const float* __restrict__ A,
                                                const unsigned short* __restrict__ wf,
                                                const float* __restrict__ bias,
                                                const float* __restrict__ dinv,
                                                void* __restrict__ Cout, int M, int K) {
  const int N = NT * 16;
  const int lane = threadIdx.x;
  const int q = lane >> 4, c16 = lane & 15;
  const int row0 = blockIdx.x * 64;
  const float* ap[4];
#pragma unroll
  for (int m = 0; m < 4; ++m) {
    int r = row0 + m * 16 + c16;
    if (r >= M) r = M - 1;  // clamp: only pollutes OOB C rows, never stored
    ap[m] = A + (size_t)r * K + q * 8;
  }
  f32x4 acc[4][NT];
#pragma unroll
  for (int m = 0; m < 4; ++m)
#pragma unroll
    for (int nt = 0; nt < NT; ++nt) acc[m][nt] = (f32x4){0.f, 0.f, 0.f, 0.f};

  const int KS = K >> 5;
  float av[4][8];
#pragma unroll
  for (int m = 0; m < 4; ++m) {
    *(float4*)&av[m][0] = *(const float4*)(ap[m]);
    *(float4*)&av[m][4] = *(const float4*)(ap[m] + 4);
  }
  for (int ks = 0; ks < KS; ++ks) {
    // truncation split: ahi = top16(a); alo = trunc16(a - ahi). v_perm packs 2 elems/op.
    frag8 ahi[4], alo[4];
#pragma unroll
    for (int m = 0; m < 4; ++m) {
      float res[8];
#pragma unroll
      for (int i = 0; i < 8; ++i) {
        union { unsigned u; float f; } t; t.u = fbits(av[m][i]) & 0xffff0000u;
        res[i] = av[m][i] - t.f;
      }
#pragma unroll
      for (int j = 0; j < 4; ++j) {
        ahi[m].u[j] = __builtin_amdgcn_perm(fbits(av[m][2 * j + 1]), fbits(av[m][2 * j]),
                                            0x07060302u);
        alo[m].u[j] = __builtin_amdgcn_perm(fbits(res[2 * j + 1]), fbits(res[2 * j]),
                                            0x07060302u);
      }
    }
    if (ks + 1 < KS) {  // prefetch next A K-slice
#pragma unroll
      for (int m = 0; m < 4; ++m) {
        *(float4*)&av[m][0] = *(const float4*)(ap[m] + (ks + 1) * 32);
        *(float4*)&av[m][4] = *(const float4*)(ap[m] + (ks + 1) * 32 + 4);
      }
    }
    const unsigned short* wp = wf + (size_t)ks * NT * 1024 + lane * 16;
#pragma unroll
    for (int nt = 0; nt < NT; ++nt) {
      short8 bhi = *(const short8*)(wp);
      short8 blo = *(const short8*)(wp + 8);
#pragma unroll
      for (int m = 0; m < 4; ++m) {
        acc[m][nt] = __builtin_amdgcn_mfma_f32_16x16x32_bf16(ahi[m].s, bhi, acc[m][nt], 0, 0, 0);
        acc[m][nt] = __builtin_amdgcn_mfma_f32_16x16x32_bf16(ahi[m].s, blo, acc[m][nt], 0, 0, 0);
        acc[m][nt] = __builtin_amdgcn_mfma_f32_16x16x32_bf16(alo[m].s, bhi, acc[m][nt], 0, 0, 0);
      }
      wp += 1024;
    }
  }
  // C/D layout (verified m89): col = lane&15, row = (lane>>4)*4 + reg
#pragma unroll
  for (int m = 0; m < 4; ++m) {
#pragma unroll
    for (int nt = 0; nt < NT; ++nt) {
      int col = nt * 16 + c16;
      float bv = (MODE == 1) ? 0.f : bias[col];
#pragma unroll
      for (int r = 0; r < 4; ++r) {
        int gr = row0 + m * 16 + q * 4 + r;
        if (gr >= M) continue;
        float v = acc[m][nt][r];
        if (MODE == 0) {
          ((float*)Cout)[(size_t)gr * N + col] = lrelu(v + bv);
        } else if (MODE == 1) {
          ((unsigned short*)Cout)[(size_t)gr * N + col] = f2bf(v * dinv[gr]);
        } else {
          ((float*)Cout)[(size_t)gr * N + col] = v + bv;
        }
      }
    }
  }
}

// ---- gather aggregation: h[d] = lrelu((sum_e t[src_e] + t[d]) * dinv[d] + b) ----
// t is bf16, pre-scaled by dinv[src]. 16 lanes (8 bf16 each) per node.
__global__ __launch_bounds__(256) void k_gather(const int* __restrict__ rowptr,
                                                const int* __restrict__ deg,
                                                const int* __restrict__ eidx,
                                                const unsigned short* __restrict__ t,
                                                const float* __restrict__ dinv,
                                                const float* __restrict__ bias,
                                                float* __restrict__ h, int N) {
  int node = (blockIdx.x * 256 + threadIdx.x) >> 4;
  int lane = threadIdx.x & 15;
  if (node >= N) return;
  const uint4* t4 = (const uint4*)t;  // 16B = 8 bf16; row stride = 16 uint4
  int beg = rowptr[node];
  int d = deg[node];
  float acc[8] = {};
#define ADDV(v)                                         \
  {                                                     \
    unsigned dw[4] = {(v).x, (v).y, (v).z, (v).w};      \
    _Pragma("unroll") for (int i = 0; i < 4; ++i) {     \
      union { unsigned u; float f; } lo, hi;            \
      lo.u = dw[i] << 16;                               \
      hi.u = dw[i] & 0xffff0000u;                       \
      acc[2 * i] += lo.f;                               \
      acc[2 * i + 1] += hi.f;                           \
    }                                                   \
  }
  int e = 0;
  for (; e + 4 <= d; e += 4) {
    int s0 = eidx[beg + e + 0], s1 = eidx[beg + e + 1];
    int s2 = eidx[beg + e + 2], s3 = eidx[beg + e + 3];
    uint4 v0 = t4[(size_t)s0 * 16 + lane];
    uint4 v1 = t4[(size_t)s1 * 16 + lane];
    uint4 v2 = t4[(size_t)s2 * 16 + lane];
    uint4 v3 = t4[(size_t)s3 * 16 + lane];
    ADDV(v0); ADDV(v1); ADDV(v2); ADDV(v3);
  }
  for (; e < d; ++e) {
    int s = eidx[beg + e];
    uint4 v = t4[(size_t)s * 16 + lane];
    ADDV(v);
  }
  {  // self-loop term
    uint4 vs = t4[(size_t)node * 16 + lane];
    ADDV(vs);
  }
#undef ADDV
  float w = dinv[node];
  float* hp = h + (size_t)node * HID + lane * 8;
  const float* bp = bias + lane * 8;
  float4 o1, o2;
  float* o = (float*)&o1;
#pragma unroll
  for (int i = 0; i < 4; ++i) o[i] = lrelu(acc[i] * w + bp[i]);
  o = (float*)&o2;
#pragma unroll
  for (int i = 0; i < 4; ++i) o[i] = lrelu(acc[4 + i] * w + bp[4 + i]);
  *(float4*)hp = o1;
  *(float4*)(hp + 4) = o2;
}

extern "C" void kernel_launch(void* const* d_in, const int* in_sizes, int n_in,
                              void* d_out, int out_size, void* d_ws, size_t ws_size,
                              hipStream_t stream) {
  const float* x = (const float*)d_in[0];
  const int* ei = (const int*)d_in[1];
  const float* enc_W = (const float*)d_in[2];
  const float* enc_b = (const float*)d_in[3];
  const float* conv_W = (const float*)d_in[4];
  const float* conv_b = (const float*)d_in[5];
  const float* dec_W = (const float*)d_in[6];
  const float* dec_b = (const float*)d_in[7];
  float* out = (float*)d_out;

  const int IN_DIM = 256;
  const int N = in_sizes[0] / IN_DIM;  // 50000
  const int E = in_sizes[1] / 2;       // 800000
  const int* src = ei;
  const int* dst = ei + E;
  const int nb = (N + 255) / 256;

  // workspace layout
  char* wp = (char*)d_ws;
  auto alloc = [&](size_t bytes) {
    void* p = wp;
    wp += (bytes + 255) & ~(size_t)255;
    return p;
  };
  int* deg = (int*)alloc((size_t)N * 4);
  int* cursor = (int*)alloc((size_t)N * 4);  // adjacent to deg: one memset covers both
  int* rowptr = (int*)alloc((size_t)N * 4);
  int* bsum = (int*)alloc(1024);
  int* boff = (int*)alloc(1024);
  int* eidx = (int*)alloc((size_t)E * 4);
  float* dinv = (float*)alloc((size_t)N * 4);
  float* h = (float*)alloc((size_t)N * HID * 4);
  unsigned short* t = (unsigned short*)alloc((size_t)N * HID * 2);  // bf16
  unsigned short* wf_enc = (unsigned short*)alloc((size_t)8 * 8 * 64 * 16 * 2);  // K=256,N=128
  unsigned short* wf_c0 = (unsigned short*)alloc((size_t)4 * 8 * 64 * 16 * 2);   // K=128,N=128
  unsigned short* wf_c1 = (unsigned short*)alloc((size_t)4 * 8 * 64 * 16 * 2);
  unsigned short* wf_dec = (unsigned short*)alloc((size_t)4 * 4 * 64 * 16 * 2);  // K=128,N=64

  // zero deg + cursor (contiguous, each padded to 256B)
  hipMemsetAsync(deg, 0, (((size_t)N * 4 + 255) & ~(size_t)255) * 2, stream);

  // weight swizzles (one launch)
  k_wconv_all<<<36, 256, 0, stream>>>(enc_W, conv_W, dec_W, wf_enc, wf_c0, wf_c1, wf_dec);

  // normalization + CSR build
  k_deg<<<(E + 255) / 256, 256, 0, stream>>>(dst, E, deg);
  k_scan1<<<nb, 256, 0, stream>>>(deg, N, rowptr, bsum, dinv);
  k_scan2<<<1, 256, 0, stream>>>(bsum, boff, nb);
  k_scan3<<<nb, 256, 0, stream>>>(rowptr, boff, N);
  k_fill<<<(E + 255) / 256, 256, 0, stream>>>(src, dst, E, rowptr, cursor, eidx);

  const int gm = (N + 63) / 64;

  // encoder: h = lrelu(x @ enc_W + enc_b)
  k_mfma<8, 0><<<gm, 64, 0, stream>>>(x, wf_enc, enc_b, nullptr, h, N, 256);

  for (int l = 0; l < 2; ++l) {
    const unsigned short* wf = l ? wf_c1 : wf_c0;
    // t = bf16((h @ W) * dinv[row])
    k_mfma<8, 1><<<gm, 64, 0, stream>>>(h, wf, nullptr, dinv, t, N, HID);
    // h[d] = lrelu((sum_e t[src_e] + t[d]) * dinv[d] + b)
    k_gather<<<(N * 16 + 255) / 256, 256, 0, stream>>>(
        rowptr, deg, eidx, t, dinv, conv_b + (size_t)l * HID, h, N);
  }

  // decoder: out = h @ dec_W + dec_b
  k_mfma<4, 2><<<gm, 64, 0, stream>>>(h, wf_dec, dec_b, nullptr, out, N, HID);
}